// Round 1
// baseline (388.150 us; speedup 1.0000x reference)
//
#include <hip/hip_runtime.h>

// DistMult: out[n1,n2] = (input1 * w[type]) @ input2^T + bias
// n1=n2=8192, d=512, fp32 in/out.
// Pass 1: fp32->bf16 convert (w_r scale fused into A).
// Pass 2: 256x256 8-phase bf16 MFMA NT-GEMM (BK=64, 8 waves, dbuf LDS 128KiB,
//         counted vmcnt(6) pipeline, st_16x32 LDS swizzle, setprio, XCD swizzle).

#define N1 8192
#define N2 8192
#define DK 512

// 128x128 fallback params (verified kernel, kept as safety net)
#define BM 128
#define BN 128
#define BK 32

// 256x256 kernel: 8 K-tiles of 64
#define NT (DK / 64)

typedef short bf16x8 __attribute__((ext_vector_type(8)));
typedef float f32x4 __attribute__((ext_vector_type(4)));

__device__ __forceinline__ unsigned short f2bf(float f) {
    unsigned int u = __float_as_uint(f);
    u = (u + 0x7FFFu + ((u >> 16) & 1u)) >> 16;  // round-to-nearest-even
    return (unsigned short)u;
}

// One pass over both inputs: A-region gets w_r scaling, B-region straight cast.
__global__ __launch_bounds__(256) void convert_kernel(
        const float* __restrict__ in1, const float* __restrict__ in2,
        const float* __restrict__ weight, const int* __restrict__ type_index,
        unsigned short* __restrict__ a_bf, unsigned short* __restrict__ b_bf) {
    const int QA = N1 * DK / 4;
    int i = blockIdx.x * blockDim.x + threadIdx.x;
    if (i < QA) {
        float4 v = reinterpret_cast<const float4*>(in1)[i];
        int c4 = i & (DK / 4 - 1);
        float4 w = reinterpret_cast<const float4*>(weight + (size_t)(*type_index) * DK)[c4];
        ushort4 o;
        o.x = f2bf(v.x * w.x);
        o.y = f2bf(v.y * w.y);
        o.z = f2bf(v.z * w.z);
        o.w = f2bf(v.w * w.w);
        reinterpret_cast<ushort4*>(a_bf)[i] = o;
    } else {
        int j = i - QA;
        float4 v = reinterpret_cast<const float4*>(in2)[j];
        ushort4 o;
        o.x = f2bf(v.x);
        o.y = f2bf(v.y);
        o.z = f2bf(v.z);
        o.w = f2bf(v.w);
        reinterpret_cast<ushort4*>(b_bf)[j] = o;
    }
}

// ---------------------------------------------------------------------------
// 256x256 8-phase GEMM (m201-template port).
// 512 thr = 8 waves (2M x 4N). Per-wave output 128x64 = acc[8][4] f32x4.
// LDS: A [2 dbuf][2 half][128rows x 64cols bf16 = 16KB] at 0..64K, B at 64K..128K.
// st_16x32 swizzle: byte ^= ((byte>>9)&1)<<5 within each half (involution),
// applied on the READ address and (inverse = same) on the pre-swizzled global
// SOURCE address for global_load_lds (LDS dest stays linear — rule #21).
// ---------------------------------------------------------------------------
#define FENCE() asm volatile("" ::: "memory")
#define LGKM(n) asm volatile("s_waitcnt lgkmcnt(" #n ")" ::: "memory")
#define VMC(n)  asm volatile("s_waitcnt vmcnt(" #n ")" ::: "memory")
#define SB0()   __builtin_amdgcn_sched_barrier(0)
#define BARR()  do { FENCE(); __builtin_amdgcn_s_barrier(); FENCE(); } while (0)

// One C-quadrant (4 mi x 2 ni x 2 kk = 16 MFMA), setprio-wrapped (T5).
#define MMAQ(M0, N0)                                                                  \
    do {                                                                              \
        __builtin_amdgcn_s_setprio(1);                                                \
        _Pragma("unroll") for (int mi_ = 0; mi_ < 4; ++mi_)                           \
        _Pragma("unroll") for (int ni_ = 0; ni_ < 2; ++ni_)                           \
        _Pragma("unroll") for (int kk_ = 0; kk_ < 2; ++kk_)                           \
            acc[(M0) + mi_][(N0) + ni_] = __builtin_amdgcn_mfma_f32_16x16x32_bf16(    \
                af[(M0) + mi_][kk_], bfr[(N0) + ni_][kk_], acc[(M0) + mi_][(N0) + ni_], 0, 0, 0); \
        __builtin_amdgcn_s_setprio(0);                                                \
    } while (0)

// Stage one half-tile (128 rows x 64 cols = 16KB) of K-tile T: 2 gloads/thread.
// LDS dest is linear (wave-uniform base + lane*16); source carries the swizzle.
#define STAGE(srcp, matbase, h, T) do {                                               \
    char* _d = sm + (matbase) + (((T) & 1) * 32768) + (h) * 16384 + wave * 1024;      \
    __builtin_amdgcn_global_load_lds(                                                 \
        (const unsigned int*)((srcp) + (size_t)(T) * 128), (unsigned int*)_d, 16, 0, 0); \
    __builtin_amdgcn_global_load_lds(                                                 \
        (const unsigned int*)((srcp) + (size_t)(T) * 128 + 65536),                    \
        (unsigned int*)(_d + 8192), 16, 0, 0);                                        \
} while (0)

__global__ __launch_bounds__(512, 2) void gemm_256(
        const unsigned short* __restrict__ A, const unsigned short* __restrict__ B,
        const float* __restrict__ bias, float* __restrict__ C) {
    extern __shared__ char sm[];
    const int tid  = threadIdx.x;
    const int wave = tid >> 6;
    const int lane = tid & 63;
    const int quad = lane >> 4;
    const int r16  = lane & 15;
    const int wm   = wave >> 2;   // 0..1
    const int wn   = wave & 3;    // 0..3

    // Bijective XCD-aware swizzle (grid=1024, 1024%8==0): 128 consecutive
    // tiles per XCD -> A-panel reuse in that XCD's L2.
    const int bid = blockIdx.x;
    const int swz = (bid & 7) * 128 + (bid >> 3);
    const int bm = (swz >> 5) * 256;
    const int bn = (swz & 31) * 256;

    // --- staging geometry: thread covers linear LDS off O = ld*8192 + tid*16
    // within a half; logical source L = O ^ (((O>>9)&1)<<5)  (bit9 = tid bit5)
    //   row(L) = ld*64 + tid/8 ; colbyte(L) = ((tid&7)*16) ^ (((tid>>5)&1)<<5)
    const int rowh = tid >> 3;
    const int colb = ((tid & 7) * 16) ^ (((tid >> 5) & 1) << 5);
    const char* sA0 = (const char*)A + ((size_t)(bm +       rowh) * DK) * 2 + colb;
    const char* sA1 = (const char*)A + ((size_t)(bm + 128 + rowh) * DK) * 2 + colb;
    const char* sB0 = (const char*)B + ((size_t)(bn +       rowh) * DK) * 2 + colb;
    const char* sB1 = (const char*)B + ((size_t)(bn + 128 + rowh) * DK) * 2 + colb;

    f32x4 acc[8][4];
#pragma unroll
    for (int i = 0; i < 8; ++i)
#pragma unroll
        for (int j = 0; j < 4; ++j)
            acc[i][j] = (f32x4){0.f, 0.f, 0.f, 0.f};

    // --- LDS read base (swizzled). Within-half logical byte:
    //   (row)*128 + kk*64 + quad*16, row = mi*16 + r16 ; bit9 = (r16>>2)&1.
    // Bit fields are disjoint, so precompute the XOR once.
    const int flip32 = ((r16 >> 2) & 1) << 5;
    const int xoff   = (r16 * 128 + quad * 16) ^ flip32;

    // --- prologue: 7 half-tiles (tile0 complete + tile1 A0,A1,B0) = 14 loads.
    // vmcnt(6) -> oldest 8 (tile0) landed, 3 half-tiles in flight (steady state).
    STAGE(sA0, 0,     0, 0); STAGE(sA1, 0,     1, 0);
    STAGE(sB0, 65536, 0, 0); STAGE(sB1, 65536, 1, 0);
    STAGE(sA0, 0,     0, 1); STAGE(sA1, 0,     1, 1);
    STAGE(sB0, 65536, 0, 1);
    VMC(6);
    BARR();

    // --- main loop: per K-tile t, 4 phases. Per tile issue stream:
    // P1: (t+1).B1 | P2: (t+2).A0 | P3: (t+2).A1 | P4: (t+2).B0 ; vmcnt(6) @ P4.
    // Region-overwrite proof: A reads + Bg0 covered by P1 lgkmcnt(4) (issue
    // order A16,Bg0,Bg1) before P2/P3/P4 issue their replacements; Bg1 covered
    // by P3 lgkmcnt(0) before next-tile P1 issues (t+2).B1.
#pragma unroll 1
    for (int t = 0; t < NT; ++t) {
        const char* bA = sm + ((t & 1) * 32768) + wm * 16384 + xoff;
        const char* bB = sm + 65536 + ((t & 1) * 32768) + wn * 8192 + xoff;
        bf16x8 af[8][2], bfr[4][2];

        // P1 front-loaded reads: A16, then Bg0(4), then Bg1(4) — order pinned.
#pragma unroll
        for (int mi = 0; mi < 8; ++mi) {
            af[mi][0] = *(const bf16x8*)(bA + mi * 2048);
            af[mi][1] = *(const bf16x8*)(bA + mi * 2048 + 64);
        }
        FENCE();
#pragma unroll
        for (int ni = 0; ni < 2; ++ni) {
            bfr[ni][0] = *(const bf16x8*)(bB + ni * 2048);
            bfr[ni][1] = *(const bf16x8*)(bB + ni * 2048 + 64);
        }
        FENCE();
#pragma unroll
        for (int ni = 2; ni < 4; ++ni) {
            bfr[ni][0] = *(const bf16x8*)(bB + ni * 2048);
            bfr[ni][1] = *(const bf16x8*)(bB + ni * 2048 + 64);
        }
        FENCE();
        if (t + 1 < NT) STAGE(sB1, 65536, 1, t + 1);   // other dbuf: safe now
        BARR();
        LGKM(4); SB0();                                 // A16 + Bg0 complete
        MMAQ(0, 0);                                     // P1: mi0-3 x ni0-1
        BARR();

        if (t + 2 < NT) STAGE(sA0, 0, 0, t + 2);        // A0 fully read in P1
        BARR();
        MMAQ(4, 0);                                     // P2: mi4-7 x ni0-1
        BARR();

        if (t + 2 < NT) STAGE(sA1, 0, 1, t + 2);        // A1 fully read in P1
        BARR();
        LGKM(0); SB0();                                 // Bg1 complete
        MMAQ(0, 2);                                     // P3: mi0-3 x ni2-3
        BARR();

        if (t + 2 < NT) STAGE(sB0, 65536, 0, t + 2);    // B0 fully read in P1
        BARR();
        MMAQ(4, 2);                                     // P4: mi4-7 x ni2-3
        if (t < NT - 2) { VMC(6); }                     // next tile resident
        else if (t == NT - 2) { VMC(0); }               // tail drain
        BARR();
    }

    // Epilogue: C/D mapping col=lane&15, row=quad*4+reg (verified m89/m91).
    const float bv = bias[0];
#pragma unroll
    for (int mi = 0; mi < 8; ++mi) {
        const int row0 = bm + wm * 128 + mi * 16 + quad * 4;
#pragma unroll
        for (int ni = 0; ni < 4; ++ni) {
            const int col = bn + wn * 64 + ni * 16 + r16;
#pragma unroll
            for (int r = 0; r < 4; ++r)
                C[(size_t)(row0 + r) * N2 + col] = acc[mi][ni][r] + bv;
        }
    }
}

#undef STAGE
#undef MMAQ

// ---------------------------------------------------------------------------
// Fallback: the previous verified 128x128 m97-structure kernel (used only if
// the 128KiB dynamic-LDS attribute can't be set).
// ---------------------------------------------------------------------------
__global__ __launch_bounds__(256) void gemm_bt(
        const unsigned short* __restrict__ A, const unsigned short* __restrict__ B,
        const float* __restrict__ bias, float* __restrict__ C) {
    __shared__ __align__(16) unsigned short ldsA[BM * BK];  // 8 KB
    __shared__ __align__(16) unsigned short ldsB[BN * BK];  // 8 KB

    const int tid  = threadIdx.x;
    const int wave = tid >> 6;
    const int lane = tid & 63;
    const int quad = lane >> 4;
    const int r16  = lane & 15;
    const int wm   = wave & 1;
    const int wn   = wave >> 1;

    const int bm = blockIdx.y * BM;
    const int bn = blockIdx.x * BN;

    f32x4 acc[4][4];
#pragma unroll
    for (int i = 0; i < 4; ++i)
#pragma unroll
        for (int j = 0; j < 4; ++j)
            acc[i][j] = (f32x4){0.f, 0.f, 0.f, 0.f};

    const int srow = wave * 32 + (lane >> 2);
    const int scol = (lane & 3) * 8;
    const unsigned short* ag0 = A + (size_t)(bm + srow) * DK + scol;
    const unsigned short* ag1 = ag0 + 16 * DK;
    const unsigned short* bg0 = B + (size_t)(bn + srow) * DK + scol;
    const unsigned short* bg1 = bg0 + 16 * DK;

    unsigned short* la0 = &ldsA[wave * 1024];
    unsigned short* la1 = &ldsA[wave * 1024 + 512];
    unsigned short* lb0 = &ldsB[wave * 1024];
    unsigned short* lb1 = &ldsB[wave * 1024 + 512];

    for (int kt = 0; kt < DK; kt += BK) {
        __builtin_amdgcn_global_load_lds(ag0 + kt, la0, 16, 0, 0);
        __builtin_amdgcn_global_load_lds(ag1 + kt, la1, 16, 0, 0);
        __builtin_amdgcn_global_load_lds(bg0 + kt, lb0, 16, 0, 0);
        __builtin_amdgcn_global_load_lds(bg1 + kt, lb1, 16, 0, 0);
        __syncthreads();

        bf16x8 af[4], bfr[4];
#pragma unroll
        for (int mi = 0; mi < 4; ++mi)
            af[mi] = *(const bf16x8*)&ldsA[(wm * 64 + mi * 16 + r16) * BK + quad * 8];
#pragma unroll
        for (int ni = 0; ni < 4; ++ni)
            bfr[ni] = *(const bf16x8*)&ldsB[(wn * 64 + ni * 16 + r16) * BK + quad * 8];

#pragma unroll
        for (int mi = 0; mi < 4; ++mi)
#pragma unroll
            for (int ni = 0; ni < 4; ++ni)
                acc[mi][ni] = __builtin_amdgcn_mfma_f32_16x16x32_bf16(
                    af[mi], bfr[ni], acc[mi][ni], 0, 0, 0);
        __syncthreads();
    }

    const float bv = bias[0];
#pragma unroll
    for (int mi = 0; mi < 4; ++mi) {
        const int row0 = bm + wm * 64 + mi * 16 + quad * 4;
#pragma unroll
        for (int ni = 0; ni < 4; ++ni) {
            const int col = bn + wn * 64 + ni * 16 + r16;
#pragma unroll
            for (int r = 0; r < 4; ++r)
                C[(size_t)(row0 + r) * N2 + col] = acc[mi][ni][r] + bv;
        }
    }
}

// Fallback if workspace is too small for the bf16 copies (correct but slow).
__global__ void naive_kernel(const float* __restrict__ in1, const float* __restrict__ in2,
                             const float* __restrict__ weight, const int* __restrict__ type_index,
                             const float* __restrict__ bias, float* __restrict__ out) {
    int col = blockIdx.x * 16 + threadIdx.x;
    int row = blockIdx.y * 16 + threadIdx.y;
    const float* wr = weight + (size_t)(*type_index) * DK;
    float s = 0.f;
    for (int k = 0; k < DK; ++k)
        s += in1[(size_t)row * DK + k] * wr[k] * in2[(size_t)col * DK + k];
    out[(size_t)row * N2 + col] = s + bias[0];
}

extern "C" void kernel_launch(void* const* d_in, const int* in_sizes, int n_in,
                              void* d_out, int out_size, void* d_ws, size_t ws_size,
                              hipStream_t stream) {
    const float* in1  = (const float*)d_in[0];
    const float* in2  = (const float*)d_in[1];
    const float* wgt  = (const float*)d_in[2];
    const float* bias = (const float*)d_in[3];
    const int*   tix  = (const int*)d_in[4];
    float* out = (float*)d_out;

    const size_t need = 2ull * (N1 + N2) * DK;  // bf16 copies of A(scaled)+B = 16 MB
    if (ws_size >= need) {
        unsigned short* a_bf = (unsigned short*)d_ws;
        unsigned short* b_bf = a_bf + (size_t)N1 * DK;

        const int total4 = (N1 + N2) * DK / 4;
        convert_kernel<<<total4 / 256, 256, 0, stream>>>(in1, in2, wgt, tix, a_bf, b_bf);

        // 128 KiB dynamic LDS needs an explicit opt-in on gfx950.
        hipError_t e = hipFuncSetAttribute(
            reinterpret_cast<const void*>(gemm_256),
            hipFuncAttributeMaxDynamicSharedMemorySize, 131072);
        if (e == hipSuccess) {
            gemm_256<<<dim3(1024), dim3(512), 131072, stream>>>(a_bf, b_bf, bias, out);
        } else {
            dim3 grid(N2 / BN, N1 / BM);
            gemm_bt<<<grid, 256, 0, stream>>>(a_bf, b_bf, bias, out);
        }
    } else {
        dim3 grid(N2 / 16, N1 / 16);
        dim3 blk(16, 16);
        naive_kernel<<<grid, blk, 0, stream>>>(in1, in2, wgt, tix, bias, out);
    }
}